// Round 1
// baseline (504.108 us; speedup 1.0000x reference)
//
#include <hip/hip_runtime.h>
#include <math.h>

#define NN 50000
#define NE 800000
#define SLOPE 0.2f

// ---------------- CSR build ----------------

__global__ void deg_kernel(const int* __restrict__ tgt, int* __restrict__ deg) {
  int e = blockIdx.x * 256 + threadIdx.x;
  if (e < NE) atomicAdd(&deg[tgt[e]], 1);
}

__global__ void scan_kernel(const int* __restrict__ deg, int* __restrict__ rowptr,
                            int* __restrict__ cursor) {
  __shared__ int sm[1024];
  const int CH = 49;  // ceil(50000/1024)
  int tid = threadIdx.x;
  int base = tid * CH;
  int s = 0;
  for (int i = 0; i < CH; ++i) {
    int idx = base + i;
    if (idx < NN) s += deg[idx];
  }
  sm[tid] = s;
  __syncthreads();
  for (int off = 1; off < 1024; off <<= 1) {
    int v = 0;
    if (tid >= off) v = sm[tid - off];
    __syncthreads();
    if (tid >= off) sm[tid] += v;
    __syncthreads();
  }
  int run = sm[tid] - s;  // exclusive prefix
  for (int i = 0; i < CH; ++i) {
    int idx = base + i;
    if (idx < NN) {
      rowptr[idx] = run;
      cursor[idx] = run;
      run += deg[idx];
    }
  }
  if (tid == 1023) rowptr[NN] = run;
}

__global__ void scatter_kernel(const int* __restrict__ src, const int* __restrict__ tgt,
                               int* __restrict__ cursor, int2* __restrict__ csr) {
  int e = blockIdx.x * 256 + threadIdx.x;
  if (e < NE) {
    int t = tgt[e];
    int pos = atomicAdd(&cursor[t], 1);
    csr[pos] = make_int2(src[e], e);
  }
}

// ---------------- fused x_l / x_r GEMM ----------------
// out_combined[n][0:128]=x_l, [128:256]=x_r. 64-node x 64-col tiles, 4x4 per thread.

__launch_bounds__(256)
__global__ void gemm_kernel(const float* __restrict__ x,
                            const float* __restrict__ W_l, const float* __restrict__ b_l,
                            const float* __restrict__ W_r, const float* __restrict__ b_r,
                            float* __restrict__ x_l, float* __restrict__ x_r) {
  __shared__ float xs[64 * 68];   // [node][k-half], padded stride 68
  __shared__ float wsm[64 * 64];  // [k-half][col]
  int tid = threadIdx.x;
  int cx = tid & 15;   // col quad
  int rn = tid >> 4;   // node quad
  int n0 = blockIdx.x * 64;
  int gc0 = blockIdx.y * 64;           // global combined col base (0,64,128,192)
  bool isL = (gc0 < 128);
  const float* W = isL ? W_l : W_r;
  int cb = gc0 & 127;

  float acc[4][4];
#pragma unroll
  for (int i = 0; i < 4; ++i)
#pragma unroll
    for (int j = 0; j < 4; ++j) acc[i][j] = 0.f;

  for (int kb = 0; kb < 128; kb += 64) {
#pragma unroll
    for (int r = 0; r < 4; ++r) {
      int q = tid + r * 256;
      int n = q >> 4, k4 = q & 15;
      float4 v = make_float4(0.f, 0.f, 0.f, 0.f);
      int gn = n0 + n;
      if (gn < NN) v = *(const float4*)(x + (size_t)gn * 128 + kb + 4 * k4);
      *(float4*)&xs[n * 68 + 4 * k4] = v;
    }
#pragma unroll
    for (int r = 0; r < 4; ++r) {
      int q = tid + r * 256;
      int kk = q >> 4, c4 = q & 15;
      float4 wv = *(const float4*)(W + (size_t)(kb + kk) * 128 + cb + 4 * c4);
      *(float4*)&wsm[kk * 64 + 4 * c4] = wv;
    }
    __syncthreads();
#pragma unroll 8
    for (int k = 0; k < 64; ++k) {
      float4 wv = *(const float4*)&wsm[k * 64 + 4 * cx];
#pragma unroll
      for (int i = 0; i < 4; ++i) {
        float xv = xs[(4 * rn + i) * 68 + k];
        acc[i][0] = fmaf(xv, wv.x, acc[i][0]);
        acc[i][1] = fmaf(xv, wv.y, acc[i][1]);
        acc[i][2] = fmaf(xv, wv.z, acc[i][2]);
        acc[i][3] = fmaf(xv, wv.w, acc[i][3]);
      }
    }
    __syncthreads();
  }

  const float* bptr = isL ? b_l : b_r;
  float* optr = isL ? x_l : x_r;
  int cc = cb + 4 * cx;
  float4 bv = *(const float4*)(bptr + cc);
#pragma unroll
  for (int i = 0; i < 4; ++i) {
    int gn = n0 + 4 * rn + i;
    if (gn < NN) {
      float4 o = make_float4(acc[i][0] + bv.x, acc[i][1] + bv.y,
                             acc[i][2] + bv.z, acc[i][3] + bv.w);
      *(float4*)(optr + (size_t)gn * 128 + cc) = o;
    }
  }
}

// ---------------- main GATv2 kernel: one wave per target, online softmax ----------------
// lane L holds flattened channels (2L, 2L+1); head h = L>>4.
// loop_attr @ W_e == (sum of per-edge e)/deg  (linearity) -> self-loop synthesized last.

__launch_bounds__(256)
__global__ void gat_kernel(const float* __restrict__ x_l, const float* __restrict__ x_r,
                           const int* __restrict__ rowptr, const int2* __restrict__ csr,
                           const float* __restrict__ eattr, const float* __restrict__ W_e,
                           const float* __restrict__ att, const float* __restrict__ bias,
                           float* __restrict__ out) {
  int wid = threadIdx.x >> 6;
  int lane = threadIdx.x & 63;
  int t = blockIdx.x * 4 + wid;  // 12500*4 == 50000, no guard needed

  // preload W_e columns (2 per lane), att, x_r[t]
  float2 wek[16];
#pragma unroll
  for (int k = 0; k < 16; ++k)
    wek[k] = *(const float2*)(W_e + k * 128 + 2 * lane);
  float2 attv = *(const float2*)(att + 2 * lane);
  float2 xr = *(const float2*)(x_r + (size_t)t * 128 + 2 * lane);

  int start = rowptr[t], end = rowptr[t + 1];
  start = __builtin_amdgcn_readfirstlane(start);
  end = __builtin_amdgcn_readfirstlane(end);

  float mh = -INFINITY, lh = 0.f;
  float acc0 = 0.f, acc1 = 0.f;
  float es0 = 0.f, es1 = 0.f;  // running sum of e vectors (for self-loop attr)

  for (int j = start; j < end; ++j) {
    int2 ce = csr[j];
    int srcn = __builtin_amdgcn_readfirstlane(ce.x);
    int eid = __builtin_amdgcn_readfirstlane(ce.y);
    const float4* ap = (const float4*)(eattr + (size_t)eid * 16);
    float4 a0 = ap[0], a1 = ap[1], a2 = ap[2], a3 = ap[3];
    float2 xl = *(const float2*)(x_l + (size_t)srcn * 128 + 2 * lane);

    float e0 = a0.x * wek[0].x;
    e0 = fmaf(a0.y, wek[1].x, e0);  e0 = fmaf(a0.z, wek[2].x, e0);
    e0 = fmaf(a0.w, wek[3].x, e0);  e0 = fmaf(a1.x, wek[4].x, e0);
    e0 = fmaf(a1.y, wek[5].x, e0);  e0 = fmaf(a1.z, wek[6].x, e0);
    e0 = fmaf(a1.w, wek[7].x, e0);  e0 = fmaf(a2.x, wek[8].x, e0);
    e0 = fmaf(a2.y, wek[9].x, e0);  e0 = fmaf(a2.z, wek[10].x, e0);
    e0 = fmaf(a2.w, wek[11].x, e0); e0 = fmaf(a3.x, wek[12].x, e0);
    e0 = fmaf(a3.y, wek[13].x, e0); e0 = fmaf(a3.z, wek[14].x, e0);
    e0 = fmaf(a3.w, wek[15].x, e0);

    float e1 = a0.x * wek[0].y;
    e1 = fmaf(a0.y, wek[1].y, e1);  e1 = fmaf(a0.z, wek[2].y, e1);
    e1 = fmaf(a0.w, wek[3].y, e1);  e1 = fmaf(a1.x, wek[4].y, e1);
    e1 = fmaf(a1.y, wek[5].y, e1);  e1 = fmaf(a1.z, wek[6].y, e1);
    e1 = fmaf(a1.w, wek[7].y, e1);  e1 = fmaf(a2.x, wek[8].y, e1);
    e1 = fmaf(a2.y, wek[9].y, e1);  e1 = fmaf(a2.z, wek[10].y, e1);
    e1 = fmaf(a2.w, wek[11].y, e1); e1 = fmaf(a3.x, wek[12].y, e1);
    e1 = fmaf(a3.y, wek[13].y, e1); e1 = fmaf(a3.z, wek[14].y, e1);
    e1 = fmaf(a3.w, wek[15].y, e1);

    es0 += e0; es1 += e1;
    float m0 = xl.x + xr.x + e0;
    float m1 = xl.y + xr.y + e1;
    float lm0 = fmaxf(m0, 0.f) + SLOPE * fminf(m0, 0.f);
    float lm1 = fmaxf(m1, 0.f) + SLOPE * fminf(m1, 0.f);
    float part = attv.x * lm0 + attv.y * lm1;
    part += __shfl_xor(part, 1);
    part += __shfl_xor(part, 2);
    part += __shfl_xor(part, 4);
    part += __shfl_xor(part, 8);   // s_h replicated in 16-lane head group
    float s = part;
    float nm = fmaxf(mh, s);
    float sc = __expf(mh - nm);
    float p = __expf(s - nm);
    lh = lh * sc + p;
    acc0 = fmaf(acc0, sc, p * xl.x);
    acc1 = fmaf(acc1, sc, p * xl.y);
    mh = nm;
  }

  // self-loop: attr = (sum attr)/max(deg,1)  ->  e = es/max(deg,1)
  {
    float rdeg = 1.0f / fmaxf((float)(end - start), 1.0f);
    float e0 = es0 * rdeg, e1 = es1 * rdeg;
    float2 xl = *(const float2*)(x_l + (size_t)t * 128 + 2 * lane);
    float m0 = xl.x + xr.x + e0;
    float m1 = xl.y + xr.y + e1;
    float lm0 = fmaxf(m0, 0.f) + SLOPE * fminf(m0, 0.f);
    float lm1 = fmaxf(m1, 0.f) + SLOPE * fminf(m1, 0.f);
    float part = attv.x * lm0 + attv.y * lm1;
    part += __shfl_xor(part, 1);
    part += __shfl_xor(part, 2);
    part += __shfl_xor(part, 4);
    part += __shfl_xor(part, 8);
    float s = part;
    float nm = fmaxf(mh, s);
    float sc = __expf(mh - nm);
    float p = __expf(s - nm);
    lh = lh * sc + p;
    acc0 = fmaf(acc0, sc, p * xl.x);
    acc1 = fmaf(acc1, sc, p * xl.y);
  }

  float inv = 1.0f / lh;
  float v0 = acc0 * inv, v1 = acc1 * inv;
  // head mean: sum lanes L, L+16, L+32, L+48 (same channel in each head group)
  v0 += __shfl_xor(v0, 16);
  v0 += __shfl_xor(v0, 32);
  v1 += __shfl_xor(v1, 16);
  v1 += __shfl_xor(v1, 32);
  if (lane < 16) {
    int c0 = 2 * lane;
    float o0 = v0 * 0.25f + bias[c0];
    float o1 = v1 * 0.25f + bias[c0 + 1];
    o0 = fmaxf(o0, 0.f) + SLOPE * fminf(o0, 0.f);
    o1 = fmaxf(o1, 0.f) + SLOPE * fminf(o1, 0.f);
    *(float2*)(out + (size_t)t * 32 + c0) = make_float2(o0, o1);
  }
}

// ---------------- launch ----------------

extern "C" void kernel_launch(void* const* d_in, const int* in_sizes, int n_in,
                              void* d_out, int out_size, void* d_ws, size_t ws_size,
                              hipStream_t stream) {
  const float* x = (const float*)d_in[0];
  const int* ei = (const int*)d_in[1];
  const float* eattr = (const float*)d_in[2];
  const float* W_l = (const float*)d_in[3];
  const float* b_l = (const float*)d_in[4];
  const float* W_r = (const float*)d_in[5];
  const float* b_r = (const float*)d_in[6];
  const float* W_e = (const float*)d_in[7];
  const float* att = (const float*)d_in[8];
  const float* bias = (const float*)d_in[9];
  float* out = (float*)d_out;

  char* ws = (char*)d_ws;
  int2* csr = (int2*)ws;                       // 6,400,000 B
  float* x_l = (float*)(ws + 6400000);         // 25,600,000 B
  float* x_r = (float*)(ws + 32000000);        // 25,600,000 B
  int* deg = (int*)(ws + 57600000);            // 200,000 B
  int* rowptr = (int*)(ws + 57800000);         // 200,004 B
  int* cursor = (int*)(ws + 58000016);         // 200,000 B  (total ~58.2 MB)

  hipMemsetAsync(deg, 0, NN * sizeof(int), stream);
  deg_kernel<<<(NE + 255) / 256, 256, 0, stream>>>(ei + NE, deg);
  scan_kernel<<<1, 1024, 0, stream>>>(deg, rowptr, cursor);
  scatter_kernel<<<(NE + 255) / 256, 256, 0, stream>>>(ei, ei + NE, cursor, csr);
  gemm_kernel<<<dim3((NN + 63) / 64, 4), 256, 0, stream>>>(x, W_l, b_l, W_r, b_r, x_l, x_r);
  gat_kernel<<<NN / 4, 256, 0, stream>>>(x_l, x_r, rowptr, csr, eattr, W_e, att, bias, out);
}

// Round 2
// 471.320 us; speedup vs baseline: 1.0696x; 1.0696x over previous
//
#include <hip/hip_runtime.h>
#include <math.h>

#define NN 50000
#define NE 800000
#define SLOPE 0.2f

// ---------------- CSR build ----------------

__global__ void deg_kernel(const int* __restrict__ tgt, int* __restrict__ deg) {
  int e = blockIdx.x * 256 + threadIdx.x;
  if (e < NE) atomicAdd(&deg[tgt[e]], 1);
}

__global__ void scan_kernel(const int* __restrict__ deg, int* __restrict__ rowptr,
                            int* __restrict__ cursor) {
  __shared__ int sm[1024];
  const int CH = 49;  // ceil(50000/1024)
  int tid = threadIdx.x;
  int base = tid * CH;
  int s = 0;
  for (int i = 0; i < CH; ++i) {
    int idx = base + i;
    if (idx < NN) s += deg[idx];
  }
  sm[tid] = s;
  __syncthreads();
  for (int off = 1; off < 1024; off <<= 1) {
    int v = 0;
    if (tid >= off) v = sm[tid - off];
    __syncthreads();
    if (tid >= off) sm[tid] += v;
    __syncthreads();
  }
  int run = sm[tid] - s;  // exclusive prefix
  for (int i = 0; i < CH; ++i) {
    int idx = base + i;
    if (idx < NN) {
      rowptr[idx] = run;
      cursor[idx] = run;
      run += deg[idx];
    }
  }
  if (tid == 1023) rowptr[NN] = run;
}

__global__ void scatter_kernel(const int* __restrict__ src, const int* __restrict__ tgt,
                               int* __restrict__ cursor, int2* __restrict__ csr) {
  int e = blockIdx.x * 256 + threadIdx.x;
  if (e < NE) {
    int t = tgt[e];
    int pos = atomicAdd(&cursor[t], 1);
    csr[pos] = make_int2(src[e], e);
  }
}

// ---------------- fused x_l / x_r GEMM ----------------
// 64 nodes x 128 cols per block; y=0 -> W_l -> x_l, y=1 -> W_r -> x_r.
// Thread: cx = col quad (0..31), rn = node octet (0..7); 8 nodes x 4 cols.

__launch_bounds__(256)
__global__ void gemm_kernel(const float* __restrict__ x,
                            const float* __restrict__ W_l, const float* __restrict__ b_l,
                            const float* __restrict__ W_r, const float* __restrict__ b_r,
                            float* __restrict__ x_l, float* __restrict__ x_r) {
  __shared__ float xs[64 * 68];    // [node][k within chunk], stride 68
  __shared__ float wsm[64 * 128];  // [k within chunk][col]
  int tid = threadIdx.x;
  int cx = tid & 31;   // col quad
  int rn = tid >> 5;   // node octet
  int n0 = blockIdx.x * 64;
  bool isL = (blockIdx.y == 0);
  const float* W = isL ? W_l : W_r;

  float acc[8][4];
#pragma unroll
  for (int i = 0; i < 8; ++i)
#pragma unroll
    for (int j = 0; j < 4; ++j) acc[i][j] = 0.f;

  for (int kb = 0; kb < 128; kb += 64) {
#pragma unroll
    for (int r = 0; r < 4; ++r) {
      int q = tid + r * 256;
      int n = q >> 4, k4 = q & 15;
      float4 v = make_float4(0.f, 0.f, 0.f, 0.f);
      int gn = n0 + n;
      if (gn < NN) v = *(const float4*)(x + (size_t)gn * 128 + kb + 4 * k4);
      *(float4*)&xs[n * 68 + 4 * k4] = v;
    }
#pragma unroll
    for (int r = 0; r < 8; ++r) {
      int q = tid + r * 256;
      int kk = q >> 5, c4 = q & 31;
      float4 wv = *(const float4*)(W + (size_t)(kb + kk) * 128 + 4 * c4);
      *(float4*)&wsm[kk * 128 + 4 * c4] = wv;
    }
    __syncthreads();
#pragma unroll 2
    for (int k4 = 0; k4 < 16; ++k4) {
      float4 wv[4];
#pragma unroll
      for (int kk = 0; kk < 4; ++kk)
        wv[kk] = *(const float4*)&wsm[(4 * k4 + kk) * 128 + 4 * cx];
#pragma unroll
      for (int i = 0; i < 8; ++i) {
        float4 xv = *(const float4*)&xs[(8 * rn + i) * 68 + 4 * k4];
        acc[i][0] = fmaf(xv.x, wv[0].x, acc[i][0]);
        acc[i][1] = fmaf(xv.x, wv[0].y, acc[i][1]);
        acc[i][2] = fmaf(xv.x, wv[0].z, acc[i][2]);
        acc[i][3] = fmaf(xv.x, wv[0].w, acc[i][3]);
        acc[i][0] = fmaf(xv.y, wv[1].x, acc[i][0]);
        acc[i][1] = fmaf(xv.y, wv[1].y, acc[i][1]);
        acc[i][2] = fmaf(xv.y, wv[1].z, acc[i][2]);
        acc[i][3] = fmaf(xv.y, wv[1].w, acc[i][3]);
        acc[i][0] = fmaf(xv.z, wv[2].x, acc[i][0]);
        acc[i][1] = fmaf(xv.z, wv[2].y, acc[i][1]);
        acc[i][2] = fmaf(xv.z, wv[2].z, acc[i][2]);
        acc[i][3] = fmaf(xv.z, wv[2].w, acc[i][3]);
        acc[i][0] = fmaf(xv.w, wv[3].x, acc[i][0]);
        acc[i][1] = fmaf(xv.w, wv[3].y, acc[i][1]);
        acc[i][2] = fmaf(xv.w, wv[3].z, acc[i][2]);
        acc[i][3] = fmaf(xv.w, wv[3].w, acc[i][3]);
      }
    }
    __syncthreads();
  }

  const float* bptr = isL ? b_l : b_r;
  float* optr = isL ? x_l : x_r;
  int cc = 4 * cx;
  float4 bv = *(const float4*)(bptr + cc);
#pragma unroll
  for (int i = 0; i < 8; ++i) {
    int gn = n0 + 8 * rn + i;
    if (gn < NN) {
      float4 o = make_float4(acc[i][0] + bv.x, acc[i][1] + bv.y,
                             acc[i][2] + bv.z, acc[i][3] + bv.w);
      *(float4*)(optr + (size_t)gn * 128 + cc) = o;
    }
  }
}

// ---------------- main GATv2 kernel ----------------
// One wave handles 4 consecutive targets (amortizes W_e preload).
// lane L holds flattened channels (2L, 2L+1); head h = L>>4.
// No online max: |score| <= ~10, exp safe in fp32.
// loop_attr @ W_e == (sum of per-edge e)/deg  (linearity) -> self-loop last.

#define EDGE_PROC(AV, XL)                                              \
  {                                                                    \
    float e0 = AV[0] * wek[0].x;                                       \
    e0 = fmaf(AV[1], wek[1].x, e0);   e0 = fmaf(AV[2], wek[2].x, e0);  \
    e0 = fmaf(AV[3], wek[3].x, e0);   e0 = fmaf(AV[4], wek[4].x, e0);  \
    e0 = fmaf(AV[5], wek[5].x, e0);   e0 = fmaf(AV[6], wek[6].x, e0);  \
    e0 = fmaf(AV[7], wek[7].x, e0);   e0 = fmaf(AV[8], wek[8].x, e0);  \
    e0 = fmaf(AV[9], wek[9].x, e0);   e0 = fmaf(AV[10], wek[10].x, e0);\
    e0 = fmaf(AV[11], wek[11].x, e0); e0 = fmaf(AV[12], wek[12].x, e0);\
    e0 = fmaf(AV[13], wek[13].x, e0); e0 = fmaf(AV[14], wek[14].x, e0);\
    e0 = fmaf(AV[15], wek[15].x, e0);                                  \
    float e1 = AV[0] * wek[0].y;                                       \
    e1 = fmaf(AV[1], wek[1].y, e1);   e1 = fmaf(AV[2], wek[2].y, e1);  \
    e1 = fmaf(AV[3], wek[3].y, e1);   e1 = fmaf(AV[4], wek[4].y, e1);  \
    e1 = fmaf(AV[5], wek[5].y, e1);   e1 = fmaf(AV[6], wek[6].y, e1);  \
    e1 = fmaf(AV[7], wek[7].y, e1);   e1 = fmaf(AV[8], wek[8].y, e1);  \
    e1 = fmaf(AV[9], wek[9].y, e1);   e1 = fmaf(AV[10], wek[10].y, e1);\
    e1 = fmaf(AV[11], wek[11].y, e1); e1 = fmaf(AV[12], wek[12].y, e1);\
    e1 = fmaf(AV[13], wek[13].y, e1); e1 = fmaf(AV[14], wek[14].y, e1);\
    e1 = fmaf(AV[15], wek[15].y, e1);                                  \
    es0 += e0; es1 += e1;                                              \
    float m0 = (XL.x + xr.x) + e0;                                     \
    float m1 = (XL.y + xr.y) + e1;                                     \
    float lm0 = fmaf(SLOPE, fminf(m0, 0.f), fmaxf(m0, 0.f));           \
    float lm1 = fmaf(SLOPE, fminf(m1, 0.f), fmaxf(m1, 0.f));           \
    float part = fmaf(attv.y, lm1, attv.x * lm0);                      \
    part += __shfl_xor(part, 1);                                       \
    part += __shfl_xor(part, 2);                                       \
    part += __shfl_xor(part, 4);                                       \
    part += __shfl_xor(part, 8);                                       \
    float p = __expf(part);                                            \
    lh += p;                                                           \
    acc0 = fmaf(p, XL.x, acc0);                                        \
    acc1 = fmaf(p, XL.y, acc1);                                        \
  }

__launch_bounds__(256)
__global__ void gat_kernel(const float* __restrict__ x_l, const float* __restrict__ x_r,
                           const int* __restrict__ rowptr, const int2* __restrict__ csr,
                           const float* __restrict__ eattr, const float* __restrict__ W_e,
                           const float* __restrict__ att, const float* __restrict__ bias,
                           float* __restrict__ out) {
  int wid = threadIdx.x >> 6;
  int lane = threadIdx.x & 63;
  int tbase = (blockIdx.x * 4 + wid) * 4;  // 3125*4*4 == 50000

  float2 wek[16];
#pragma unroll
  for (int k = 0; k < 16; ++k)
    wek[k] = *(const float2*)(W_e + k * 128 + 2 * lane);
  float2 attv = *(const float2*)(att + 2 * lane);
  float bv = bias[(2 * lane) & 31];           // lanes<16 use it; harmless else
  float bv1 = bias[((2 * lane) & 31) + 1];

  for (int tt = 0; tt < 4; ++tt) {
    int t = tbase + tt;
    float2 xr = *(const float2*)(x_r + (size_t)t * 128 + 2 * lane);
    int start = __builtin_amdgcn_readfirstlane(rowptr[t]);
    int end = __builtin_amdgcn_readfirstlane(rowptr[t + 1]);

    float lh = 0.f, acc0 = 0.f, acc1 = 0.f, es0 = 0.f, es1 = 0.f;

    int j = start;
    for (; j + 2 <= end; j += 2) {
      int2 ceA = csr[j];
      int2 ceB = csr[j + 1];
      int srcA = __builtin_amdgcn_readfirstlane(ceA.x);
      int eidA = __builtin_amdgcn_readfirstlane(ceA.y);
      int srcB = __builtin_amdgcn_readfirstlane(ceB.x);
      int eidB = __builtin_amdgcn_readfirstlane(ceB.y);
      const float* apA = eattr + (size_t)eidA * 16;
      const float* apB = eattr + (size_t)eidB * 16;
      float aA[16], aB[16];
#pragma unroll
      for (int k = 0; k < 16; ++k) aA[k] = apA[k];
#pragma unroll
      for (int k = 0; k < 16; ++k) aB[k] = apB[k];
      float2 xlA = *(const float2*)(x_l + (size_t)srcA * 128 + 2 * lane);
      float2 xlB = *(const float2*)(x_l + (size_t)srcB * 128 + 2 * lane);
      EDGE_PROC(aA, xlA)
      EDGE_PROC(aB, xlB)
    }
    if (j < end) {
      int2 ce = csr[j];
      int srcn = __builtin_amdgcn_readfirstlane(ce.x);
      int eid = __builtin_amdgcn_readfirstlane(ce.y);
      const float* ap = eattr + (size_t)eid * 16;
      float aC[16];
#pragma unroll
      for (int k = 0; k < 16; ++k) aC[k] = ap[k];
      float2 xlC = *(const float2*)(x_l + (size_t)srcn * 128 + 2 * lane);
      EDGE_PROC(aC, xlC)
    }

    // self-loop: e = es / max(deg,1); message source is x_l[t]
    {
      float rdeg = 1.0f / fmaxf((float)(end - start), 1.0f);
      float e0 = es0 * rdeg, e1 = es1 * rdeg;
      float2 xl = *(const float2*)(x_l + (size_t)t * 128 + 2 * lane);
      float m0 = (xl.x + xr.x) + e0;
      float m1 = (xl.y + xr.y) + e1;
      float lm0 = fmaf(SLOPE, fminf(m0, 0.f), fmaxf(m0, 0.f));
      float lm1 = fmaf(SLOPE, fminf(m1, 0.f), fmaxf(m1, 0.f));
      float part = fmaf(attv.y, lm1, attv.x * lm0);
      part += __shfl_xor(part, 1);
      part += __shfl_xor(part, 2);
      part += __shfl_xor(part, 4);
      part += __shfl_xor(part, 8);
      float p = __expf(part);
      lh += p;
      acc0 = fmaf(p, xl.x, acc0);
      acc1 = fmaf(p, xl.y, acc1);
    }

    float inv = 1.0f / lh;
    float v0 = acc0 * inv, v1 = acc1 * inv;
    // head mean: lanes L, L+16, L+32, L+48 hold same within-head channel
    v0 += __shfl_xor(v0, 16);
    v0 += __shfl_xor(v0, 32);
    v1 += __shfl_xor(v1, 16);
    v1 += __shfl_xor(v1, 32);
    if (lane < 16) {
      float o0 = fmaf(v0, 0.25f, bv);
      float o1 = fmaf(v1, 0.25f, bv1);
      o0 = fmaf(SLOPE, fminf(o0, 0.f), fmaxf(o0, 0.f));
      o1 = fmaf(SLOPE, fminf(o1, 0.f), fmaxf(o1, 0.f));
      *(float2*)(out + (size_t)t * 32 + 2 * lane) = make_float2(o0, o1);
    }
  }
}

// ---------------- launch ----------------

extern "C" void kernel_launch(void* const* d_in, const int* in_sizes, int n_in,
                              void* d_out, int out_size, void* d_ws, size_t ws_size,
                              hipStream_t stream) {
  const float* x = (const float*)d_in[0];
  const int* ei = (const int*)d_in[1];
  const float* eattr = (const float*)d_in[2];
  const float* W_l = (const float*)d_in[3];
  const float* b_l = (const float*)d_in[4];
  const float* W_r = (const float*)d_in[5];
  const float* b_r = (const float*)d_in[6];
  const float* W_e = (const float*)d_in[7];
  const float* att = (const float*)d_in[8];
  const float* bias = (const float*)d_in[9];
  float* out = (float*)d_out;

  char* ws = (char*)d_ws;
  int2* csr = (int2*)ws;                       // 6,400,000 B
  float* x_l = (float*)(ws + 6400000);         // 25,600,000 B
  float* x_r = (float*)(ws + 32000000);        // 25,600,000 B
  int* deg = (int*)(ws + 57600000);            // 200,000 B
  int* rowptr = (int*)(ws + 57800000);         // 200,004 B
  int* cursor = (int*)(ws + 58000016);         // 200,000 B

  hipMemsetAsync(deg, 0, NN * sizeof(int), stream);
  deg_kernel<<<(NE + 255) / 256, 256, 0, stream>>>(ei + NE, deg);
  scan_kernel<<<1, 1024, 0, stream>>>(deg, rowptr, cursor);
  scatter_kernel<<<(NE + 255) / 256, 256, 0, stream>>>(ei, ei + NE, cursor, csr);
  gemm_kernel<<<dim3((NN + 63) / 64, 2), 256, 0, stream>>>(x, W_l, b_l, W_r, b_r, x_l, x_r);
  gat_kernel<<<NN / 16, 256, 0, stream>>>(x_l, x_r, rowptr, csr, eattr, W_e, att, bias, out);
}

// Round 3
// 348.398 us; speedup vs baseline: 1.4469x; 1.3528x over previous
//
#include <hip/hip_runtime.h>
#include <math.h>

#define NN 50000
#define NE 800000
#define SLOPE 0.2f
#define NB 49  // ceil(50000 / 1024)

// ---------------- CSR build ----------------

__global__ void deg_kernel(const int* __restrict__ tgt, int* __restrict__ deg) {
  int e = blockIdx.x * 256 + threadIdx.x;
  if (e < NE) atomicAdd(&deg[tgt[e]], 1);
}

// level-1: per-block (1024-element chunk) sums
__global__ void partial_kernel(const int* __restrict__ deg, int* __restrict__ psum) {
  int b = blockIdx.x;
  int base = b * 1024 + threadIdx.x * 4;
  int s = 0;
  if (base + 3 < NN) {
    int4 v = *(const int4*)(deg + base);
    s = v.x + v.y + v.z + v.w;
  } else {
#pragma unroll
    for (int i = 0; i < 4; ++i)
      if (base + i < NN) s += deg[base + i];
  }
  s += __shfl_xor(s, 1);
  s += __shfl_xor(s, 2);
  s += __shfl_xor(s, 4);
  s += __shfl_xor(s, 8);
  s += __shfl_xor(s, 16);
  s += __shfl_xor(s, 32);
  __shared__ int wsum[4];
  if ((threadIdx.x & 63) == 0) wsum[threadIdx.x >> 6] = s;
  __syncthreads();
  if (threadIdx.x == 0) psum[b] = wsum[0] + wsum[1] + wsum[2] + wsum[3];
}

// level-2: scan the 49 partials with one wave
__global__ void scanpart_kernel(const int* __restrict__ psum, int* __restrict__ offs,
                                int* __restrict__ rowptr) {
  int lane = threadIdx.x;
  int mine = (lane < NB) ? psum[lane] : 0;
  int v = mine;
#pragma unroll
  for (int off = 1; off < 64; off <<= 1) {
    int u = __shfl_up(v, off);
    if (lane >= off) v += u;
  }
  if (lane < NB) offs[lane] = v - mine;  // exclusive
  if (lane == 63) rowptr[NN] = v;        // grand total (lanes >= NB added 0)
}

// level-3: per-chunk rescan + global offset -> rowptr & cursor
__global__ void final_kernel(const int* __restrict__ deg, const int* __restrict__ offs,
                             int* __restrict__ rowptr, int* __restrict__ cursor) {
  int b = blockIdx.x;
  int t = threadIdx.x;
  int base = b * 1024 + t * 4;
  int d0 = 0, d1 = 0, d2 = 0, d3 = 0;
  if (base + 3 < NN) {
    int4 v = *(const int4*)(deg + base);
    d0 = v.x; d1 = v.y; d2 = v.z; d3 = v.w;
  } else {
    if (base < NN) d0 = deg[base];
    if (base + 1 < NN) d1 = deg[base + 1];
    if (base + 2 < NN) d2 = deg[base + 2];
  }
  int s = d0 + d1 + d2 + d3;
  int lane = t & 63, w = t >> 6;
  int v = s;
#pragma unroll
  for (int off = 1; off < 64; off <<= 1) {
    int u = __shfl_up(v, off);
    if (lane >= off) v += u;
  }
  __shared__ int wtot[4];
  if (lane == 63) wtot[w] = v;
  __syncthreads();
  int woff = 0;
#pragma unroll
  for (int i = 0; i < 4; ++i)
    if (i < w) woff += wtot[i];
  int run = offs[b] + woff + (v - s);
  if (base < NN)     { rowptr[base] = run;     cursor[base] = run;     run += d0; }
  if (base + 1 < NN) { rowptr[base + 1] = run; cursor[base + 1] = run; run += d1; }
  if (base + 2 < NN) { rowptr[base + 2] = run; cursor[base + 2] = run; run += d2; }
  if (base + 3 < NN) { rowptr[base + 3] = run; cursor[base + 3] = run; }
}

__global__ void scatter_kernel(const int* __restrict__ src, const int* __restrict__ tgt,
                               int* __restrict__ cursor, int2* __restrict__ csr) {
  int e = blockIdx.x * 256 + threadIdx.x;
  if (e < NE) {
    int t = tgt[e];
    int pos = atomicAdd(&cursor[t], 1);
    csr[pos] = make_int2(src[e], e);
  }
}

// ---------------- fused x_l / x_r GEMM ----------------
// 64 nodes x 128 cols per block; y=0 -> W_l -> x_l, y=1 -> W_r -> x_r.

__launch_bounds__(256)
__global__ void gemm_kernel(const float* __restrict__ x,
                            const float* __restrict__ W_l, const float* __restrict__ b_l,
                            const float* __restrict__ W_r, const float* __restrict__ b_r,
                            float* __restrict__ x_l, float* __restrict__ x_r) {
  __shared__ float xs[64 * 68];    // [node][k within chunk], stride 68
  __shared__ float wsm[64 * 128];  // [k within chunk][col]
  int tid = threadIdx.x;
  int cx = tid & 31;   // col quad
  int rn = tid >> 5;   // node octet
  int n0 = blockIdx.x * 64;
  bool isL = (blockIdx.y == 0);
  const float* W = isL ? W_l : W_r;

  float acc[8][4];
#pragma unroll
  for (int i = 0; i < 8; ++i)
#pragma unroll
    for (int j = 0; j < 4; ++j) acc[i][j] = 0.f;

  for (int kb = 0; kb < 128; kb += 64) {
#pragma unroll
    for (int r = 0; r < 4; ++r) {
      int q = tid + r * 256;
      int n = q >> 4, k4 = q & 15;
      float4 v = make_float4(0.f, 0.f, 0.f, 0.f);
      int gn = n0 + n;
      if (gn < NN) v = *(const float4*)(x + (size_t)gn * 128 + kb + 4 * k4);
      *(float4*)&xs[n * 68 + 4 * k4] = v;
    }
#pragma unroll
    for (int r = 0; r < 8; ++r) {
      int q = tid + r * 256;
      int kk = q >> 5, c4 = q & 31;
      float4 wv = *(const float4*)(W + (size_t)(kb + kk) * 128 + 4 * c4);
      *(float4*)&wsm[kk * 128 + 4 * c4] = wv;
    }
    __syncthreads();
#pragma unroll 2
    for (int k4 = 0; k4 < 16; ++k4) {
      float4 wv[4];
#pragma unroll
      for (int kk = 0; kk < 4; ++kk)
        wv[kk] = *(const float4*)&wsm[(4 * k4 + kk) * 128 + 4 * cx];
#pragma unroll
      for (int i = 0; i < 8; ++i) {
        float4 xv = *(const float4*)&xs[(8 * rn + i) * 68 + 4 * k4];
        acc[i][0] = fmaf(xv.x, wv[0].x, acc[i][0]);
        acc[i][1] = fmaf(xv.x, wv[0].y, acc[i][1]);
        acc[i][2] = fmaf(xv.x, wv[0].z, acc[i][2]);
        acc[i][3] = fmaf(xv.x, wv[0].w, acc[i][3]);
        acc[i][0] = fmaf(xv.y, wv[1].x, acc[i][0]);
        acc[i][1] = fmaf(xv.y, wv[1].y, acc[i][1]);
        acc[i][2] = fmaf(xv.y, wv[1].z, acc[i][2]);
        acc[i][3] = fmaf(xv.y, wv[1].w, acc[i][3]);
        acc[i][0] = fmaf(xv.z, wv[2].x, acc[i][0]);
        acc[i][1] = fmaf(xv.z, wv[2].y, acc[i][1]);
        acc[i][2] = fmaf(xv.z, wv[2].z, acc[i][2]);
        acc[i][3] = fmaf(xv.z, wv[2].w, acc[i][3]);
        acc[i][0] = fmaf(xv.w, wv[3].x, acc[i][0]);
        acc[i][1] = fmaf(xv.w, wv[3].y, acc[i][1]);
        acc[i][2] = fmaf(xv.w, wv[3].z, acc[i][2]);
        acc[i][3] = fmaf(xv.w, wv[3].w, acc[i][3]);
      }
    }
    __syncthreads();
  }

  const float* bptr = isL ? b_l : b_r;
  float* optr = isL ? x_l : x_r;
  int cc = 4 * cx;
  float4 bv = *(const float4*)(bptr + cc);
#pragma unroll
  for (int i = 0; i < 8; ++i) {
    int gn = n0 + 8 * rn + i;
    if (gn < NN) {
      float4 o = make_float4(acc[i][0] + bv.x, acc[i][1] + bv.y,
                             acc[i][2] + bv.z, acc[i][3] + bv.w);
      *(float4*)(optr + (size_t)gn * 128 + cc) = o;
    }
  }
}

// ---------------- main GATv2 kernel ----------------
// One wave handles 4 consecutive targets. lane L holds channels (2L, 2L+1);
// head h = L>>4. No online max (|score| small, fp32 exp safe).
// loop_attr @ W_e == (sum of per-edge e)/deg  (linearity) -> self-loop last.

#define EDGE_PROC(AV, XL)                                              \
  {                                                                    \
    float e0 = AV[0] * wek[0].x;                                       \
    e0 = fmaf(AV[1], wek[1].x, e0);   e0 = fmaf(AV[2], wek[2].x, e0);  \
    e0 = fmaf(AV[3], wek[3].x, e0);   e0 = fmaf(AV[4], wek[4].x, e0);  \
    e0 = fmaf(AV[5], wek[5].x, e0);   e0 = fmaf(AV[6], wek[6].x, e0);  \
    e0 = fmaf(AV[7], wek[7].x, e0);   e0 = fmaf(AV[8], wek[8].x, e0);  \
    e0 = fmaf(AV[9], wek[9].x, e0);   e0 = fmaf(AV[10], wek[10].x, e0);\
    e0 = fmaf(AV[11], wek[11].x, e0); e0 = fmaf(AV[12], wek[12].x, e0);\
    e0 = fmaf(AV[13], wek[13].x, e0); e0 = fmaf(AV[14], wek[14].x, e0);\
    e0 = fmaf(AV[15], wek[15].x, e0);                                  \
    float e1 = AV[0] * wek[0].y;                                       \
    e1 = fmaf(AV[1], wek[1].y, e1);   e1 = fmaf(AV[2], wek[2].y, e1);  \
    e1 = fmaf(AV[3], wek[3].y, e1);   e1 = fmaf(AV[4], wek[4].y, e1);  \
    e1 = fmaf(AV[5], wek[5].y, e1);   e1 = fmaf(AV[6], wek[6].y, e1);  \
    e1 = fmaf(AV[7], wek[7].y, e1);   e1 = fmaf(AV[8], wek[8].y, e1);  \
    e1 = fmaf(AV[9], wek[9].y, e1);   e1 = fmaf(AV[10], wek[10].y, e1);\
    e1 = fmaf(AV[11], wek[11].y, e1); e1 = fmaf(AV[12], wek[12].y, e1);\
    e1 = fmaf(AV[13], wek[13].y, e1); e1 = fmaf(AV[14], wek[14].y, e1);\
    e1 = fmaf(AV[15], wek[15].y, e1);                                  \
    es0 += e0; es1 += e1;                                              \
    float m0 = (XL.x + xr.x) + e0;                                     \
    float m1 = (XL.y + xr.y) + e1;                                     \
    float lm0 = fmaf(SLOPE, fminf(m0, 0.f), fmaxf(m0, 0.f));           \
    float lm1 = fmaf(SLOPE, fminf(m1, 0.f), fmaxf(m1, 0.f));           \
    float part = fmaf(attv.y, lm1, attv.x * lm0);                      \
    part += __shfl_xor(part, 1);                                       \
    part += __shfl_xor(part, 2);                                       \
    part += __shfl_xor(part, 4);                                       \
    part += __shfl_xor(part, 8);                                       \
    float p = __expf(part);                                            \
    lh += p;                                                           \
    acc0 = fmaf(p, XL.x, acc0);                                        \
    acc1 = fmaf(p, XL.y, acc1);                                        \
  }

__launch_bounds__(256)
__global__ void gat_kernel(const float* __restrict__ x_l, const float* __restrict__ x_r,
                           const int* __restrict__ rowptr, const int2* __restrict__ csr,
                           const float* __restrict__ eattr, const float* __restrict__ W_e,
                           const float* __restrict__ att, const float* __restrict__ bias,
                           float* __restrict__ out) {
  int wid = threadIdx.x >> 6;
  int lane = threadIdx.x & 63;
  int tbase = (blockIdx.x * 4 + wid) * 4;  // 3125*4*4 == 50000

  float2 wek[16];
#pragma unroll
  for (int k = 0; k < 16; ++k)
    wek[k] = *(const float2*)(W_e + k * 128 + 2 * lane);
  float2 attv = *(const float2*)(att + 2 * lane);
  float bv = bias[(2 * lane) & 31];
  float bv1 = bias[((2 * lane) & 31) + 1];

  for (int tt = 0; tt < 4; ++tt) {
    int t = tbase + tt;
    float2 xr = *(const float2*)(x_r + (size_t)t * 128 + 2 * lane);
    int start = __builtin_amdgcn_readfirstlane(rowptr[t]);
    int end = __builtin_amdgcn_readfirstlane(rowptr[t + 1]);

    float lh = 0.f, acc0 = 0.f, acc1 = 0.f, es0 = 0.f, es1 = 0.f;

    int j = start;
    for (; j + 2 <= end; j += 2) {
      int2 ceA = csr[j];
      int2 ceB = csr[j + 1];
      int srcA = __builtin_amdgcn_readfirstlane(ceA.x);
      int eidA = __builtin_amdgcn_readfirstlane(ceA.y);
      int srcB = __builtin_amdgcn_readfirstlane(ceB.x);
      int eidB = __builtin_amdgcn_readfirstlane(ceB.y);
      const float* apA = eattr + (size_t)eidA * 16;
      const float* apB = eattr + (size_t)eidB * 16;
      float aA[16], aB[16];
#pragma unroll
      for (int k = 0; k < 16; ++k) aA[k] = apA[k];
#pragma unroll
      for (int k = 0; k < 16; ++k) aB[k] = apB[k];
      float2 xlA = *(const float2*)(x_l + (size_t)srcA * 128 + 2 * lane);
      float2 xlB = *(const float2*)(x_l + (size_t)srcB * 128 + 2 * lane);
      EDGE_PROC(aA, xlA)
      EDGE_PROC(aB, xlB)
    }
    if (j < end) {
      int2 ce = csr[j];
      int srcn = __builtin_amdgcn_readfirstlane(ce.x);
      int eid = __builtin_amdgcn_readfirstlane(ce.y);
      const float* ap = eattr + (size_t)eid * 16;
      float aC[16];
#pragma unroll
      for (int k = 0; k < 16; ++k) aC[k] = ap[k];
      float2 xlC = *(const float2*)(x_l + (size_t)srcn * 128 + 2 * lane);
      EDGE_PROC(aC, xlC)
    }

    // self-loop: e = es / max(deg,1); message source is x_l[t]
    {
      float rdeg = 1.0f / fmaxf((float)(end - start), 1.0f);
      float e0 = es0 * rdeg, e1 = es1 * rdeg;
      float2 xl = *(const float2*)(x_l + (size_t)t * 128 + 2 * lane);
      float m0 = (xl.x + xr.x) + e0;
      float m1 = (xl.y + xr.y) + e1;
      float lm0 = fmaf(SLOPE, fminf(m0, 0.f), fmaxf(m0, 0.f));
      float lm1 = fmaf(SLOPE, fminf(m1, 0.f), fmaxf(m1, 0.f));
      float part = fmaf(attv.y, lm1, attv.x * lm0);
      part += __shfl_xor(part, 1);
      part += __shfl_xor(part, 2);
      part += __shfl_xor(part, 4);
      part += __shfl_xor(part, 8);
      float p = __expf(part);
      lh += p;
      acc0 = fmaf(p, xl.x, acc0);
      acc1 = fmaf(p, xl.y, acc1);
    }

    float inv = 1.0f / lh;
    float v0 = acc0 * inv, v1 = acc1 * inv;
    v0 += __shfl_xor(v0, 16);
    v0 += __shfl_xor(v0, 32);
    v1 += __shfl_xor(v1, 16);
    v1 += __shfl_xor(v1, 32);
    if (lane < 16) {
      float o0 = fmaf(v0, 0.25f, bv);
      float o1 = fmaf(v1, 0.25f, bv1);
      o0 = fmaf(SLOPE, fminf(o0, 0.f), fmaxf(o0, 0.f));
      o1 = fmaf(SLOPE, fminf(o1, 0.f), fmaxf(o1, 0.f));
      *(float2*)(out + (size_t)t * 32 + 2 * lane) = make_float2(o0, o1);
    }
  }
}

// ---------------- launch ----------------

extern "C" void kernel_launch(void* const* d_in, const int* in_sizes, int n_in,
                              void* d_out, int out_size, void* d_ws, size_t ws_size,
                              hipStream_t stream) {
  const float* x = (const float*)d_in[0];
  const int* ei = (const int*)d_in[1];
  const float* eattr = (const float*)d_in[2];
  const float* W_l = (const float*)d_in[3];
  const float* b_l = (const float*)d_in[4];
  const float* W_r = (const float*)d_in[5];
  const float* b_r = (const float*)d_in[6];
  const float* W_e = (const float*)d_in[7];
  const float* att = (const float*)d_in[8];
  const float* bias = (const float*)d_in[9];
  float* out = (float*)d_out;

  char* ws = (char*)d_ws;
  int2* csr = (int2*)ws;                       // 6,400,000 B
  float* x_l = (float*)(ws + 6400000);         // 25,600,000 B
  float* x_r = (float*)(ws + 32000000);        // 25,600,000 B
  int* deg = (int*)(ws + 57600000);            // 200,000 B
  int* rowptr = (int*)(ws + 57800000);         // 200,004 B
  int* cursor = (int*)(ws + 58000016);         // 200,000 B
  int* psum = (int*)(ws + 58200016);           // 196 B
  int* offs = (int*)(ws + 58200512);           // 196 B

  hipMemsetAsync(deg, 0, NN * sizeof(int), stream);
  deg_kernel<<<(NE + 255) / 256, 256, 0, stream>>>(ei + NE, deg);
  partial_kernel<<<NB, 256, 0, stream>>>(deg, psum);
  scanpart_kernel<<<1, 64, 0, stream>>>(psum, offs, rowptr);
  final_kernel<<<NB, 256, 0, stream>>>(deg, offs, rowptr, cursor);
  scatter_kernel<<<(NE + 255) / 256, 256, 0, stream>>>(ei, ei + NE, cursor, csr);
  gemm_kernel<<<dim3((NN + 63) / 64, 2), 256, 0, stream>>>(x, W_l, b_l, W_r, b_r, x_l, x_r);
  gat_kernel<<<NN / 16, 256, 0, stream>>>(x_l, x_r, rowptr, csr, eattr, W_e, att, bias, out);
}